// Round 2
// baseline (700.397 us; speedup 1.0000x reference)
//
#include <hip/hip_runtime.h>
#include <hip/hip_bf16.h>

#define C_IN   64
#define C_OUT  128
#define HH     224
#define WW     224
#define NB     16
#define OW_TILE 112

typedef __attribute__((ext_vector_type(8))) __bf16 bf16x8;
typedef __attribute__((ext_vector_type(4))) float   f32x4;

__device__ __forceinline__ unsigned short f2bf(float f) {
    union { __hip_bfloat16 b; unsigned short u; } cv;
    cv.b = __float2bfloat16(f);
    return cv.u;
}

__device__ __forceinline__ void async16(const void* g, void* l) {
    __builtin_amdgcn_global_load_lds(
        (__attribute__((address_space(1))) void*)(g),
        (__attribute__((address_space(3))) void*)(l), 16, 0, 0);
}

// ---------------- pre-pass 1: weight OIHW fp32 -> [tap][co][ci] bf16 ----------------
__global__ __launch_bounds__(256) void wconv_kernel(const float* __restrict__ w,
                                                    unsigned short* __restrict__ wr) {
    int o = (blockIdx.x * 256 + threadIdx.x) * 4;           // 4 consecutive ci
    if (o >= 9 * C_OUT * C_IN) return;
    int ci  = o & 63;
    int co  = (o >> 6) & 127;
    int tap = o >> 13;
    ushort4 r;
    r.x = f2bf(w[co * 576 + (ci + 0) * 9 + tap]);
    r.y = f2bf(w[co * 576 + (ci + 1) * 9 + tap]);
    r.z = f2bf(w[co * 576 + (ci + 2) * 9 + tap]);
    r.w = f2bf(w[co * 576 + (ci + 3) * 9 + tap]);
    *(ushort4*)(wr + o) = r;
}

// ---------------- pre-pass 2: x NCHW fp32 -> NHWC bf16 ----------------
__global__ __launch_bounds__(256) void xconv_kernel(const float* __restrict__ x,
                                                    unsigned short* __restrict__ xr) {
    __shared__ __align__(16) unsigned short tile[WW * 66];  // [w][c] padded
    int nh = blockIdx.x;
    int n = nh / HH, h = nh % HH;
    int t = threadIdx.x;
    if (t < WW) {
        const float* src = x + (size_t)n * C_IN * HH * WW + (size_t)h * WW + t;
        #pragma unroll 4
        for (int c = 0; c < C_IN; ++c) {
            tile[t * 66 + c] = f2bf(src[(size_t)c * HH * WW]);
        }
    }
    __syncthreads();
    unsigned short* dst = xr + (size_t)nh * (WW * C_IN);    // [w][c] tight
    #pragma unroll
    for (int i = 0; i < 7; ++i) {
        int ct = i * 256 + t;                                // 1792 chunks of 8 shorts
        int w8 = ct >> 3;
        int c8 = (ct & 7) * 8;
        int base = w8 * 66 + c8;
        uint4 v;
        v.x = *(const unsigned int*)&tile[base + 0];
        v.y = *(const unsigned int*)&tile[base + 2];
        v.z = *(const unsigned int*)&tile[base + 4];
        v.w = *(const unsigned int*)&tile[base + 6];
        *(uint4*)&dst[w8 * 64 + c8] = v;
    }
}

// ---------------- main: implicit GEMM, 112(ow) x 128(co) per block ----------------
__global__ __launch_bounds__(256) void conv_main(const unsigned short* __restrict__ xr,
                                                 const unsigned short* __restrict__ wr,
                                                 const float* __restrict__ bias,
                                                 float* __restrict__ out) {
    __shared__ __align__(16) unsigned short As[OW_TILE * C_IN]; // [m][ci] 14336 B
    __shared__ __align__(16) unsigned short Bs[C_OUT * C_IN];   // [co][ci] 16384 B

    const int tid  = threadIdx.x;
    const int lane = tid & 63;
    const int wave = tid >> 6;
    const int bid  = blockIdx.x;
    const int half = bid & 1;
    const int oh   = (bid >> 1) % HH;
    const int n    = bid / (HH * 2);
    const int ow0  = half * OW_TILE;
    const int row  = lane & 15;
    const int quad = lane >> 4;

    f32x4 acc[7][2] = {};
    const bf16x8 zfrag = {};

    for (int tap = 0; tap < 9; ++tap) {
        const int kh = tap / 3 - 1;
        const int kw = tap % 3 - 1;
        const int ih = oh + kh;
        if (ih < 0 || ih >= HH) continue;      // block-uniform skip

        // invalid halo row for this tap (at most one): m=0 or m=111
        const int bad = (half == 0 && kw == -1) ? 0 :
                        ((half == 1 && kw == 1) ? (OW_TILE - 1) : -1);

        // ---- stage A: 112 rows x 64 ci bf16 = 896 x 16B chunks ----
        // ALL lanes always issue (global_load_lds needs the unbroken
        // base + lane*16 LDS pattern); bad-row lanes load a clamped
        // in-bounds address and the fragment is zeroed at use.
        const size_t rowbase = (size_t)(n * HH + ih) * WW;
        #pragma unroll
        for (int i = 0; i < 4; ++i) {
            int c = i * 256 + tid;              // chunk id, need c < 896
            if (i < 3 || tid < 128) {           // wave-uniform predicate
                int m  = c >> 3;
                int ch = c & 7;
                int iw = ow0 + m + kw;
                iw = iw < 0 ? 0 : (iw > WW - 1 ? WW - 1 : iw);
                const unsigned short* src = xr + (rowbase + iw) * C_IN + ch * 8;
                async16(src, &As[c * 8]);
            }
        }
        // ---- stage B: 128 co x 64 ci bf16 = 1024 x 16B chunks ----
        const unsigned short* gb = wr + tap * (C_OUT * C_IN);
        #pragma unroll
        for (int i = 0; i < 4; ++i) {
            int c = i * 256 + tid;
            async16(gb + c * 8, &Bs[c * 8]);
        }
        __syncthreads();

        // ---- MFMA: BK=64 (two k-steps of 32) ----
        #pragma unroll
        for (int ks = 0; ks < 2; ++ks) {
            bf16x8 af[7], bfr[2];
            #pragma unroll
            for (int mi = 0; mi < 7; ++mi)
                af[mi] = *(const bf16x8*)&As[(mi * 16 + row) * C_IN + ks * 32 + quad * 8];
            // zero the (at most one) invalid halo row at point of use
            if (bad == 0 && row == 0)              af[0] = zfrag;
            if (bad == OW_TILE - 1 && row == 15)   af[6] = zfrag;
            #pragma unroll
            for (int ni = 0; ni < 2; ++ni)
                bfr[ni] = *(const bf16x8*)&Bs[(wave * 32 + ni * 16 + row) * C_IN + ks * 32 + quad * 8];
            #pragma unroll
            for (int mi = 0; mi < 7; ++mi)
                #pragma unroll
                for (int ni = 0; ni < 2; ++ni)
                    // weights as A-operand => D row = co, D col = ow (coalesced stores)
                    acc[mi][ni] = __builtin_amdgcn_mfma_f32_16x16x32_bf16(
                        bfr[ni], af[mi], acc[mi][ni], 0, 0, 0);
        }
        __syncthreads();
    }

    // ---- epilogue: D[row=co=quad*4+r (+16*ni+32*wave)][col=ow=lane&15] ----
    #pragma unroll
    for (int ni = 0; ni < 2; ++ni) {
        #pragma unroll
        for (int r = 0; r < 4; ++r) {
            int co = wave * 32 + ni * 16 + quad * 4 + r;
            float bv = bias[co];
            #pragma unroll
            for (int mi = 0; mi < 7; ++mi) {
                int ow = ow0 + mi * 16 + row;
                out[(((size_t)n * C_OUT + co) * HH + oh) * WW + ow] = acc[mi][ni][r] + bv;
            }
        }
    }
}

// ---------------- fallback: naive fp32 direct conv (if ws too small) ----------------
__global__ __launch_bounds__(256) void conv_naive(const float* __restrict__ x,
                                                  const float* __restrict__ w,
                                                  const float* __restrict__ bias,
                                                  float* __restrict__ out) {
    size_t idx = (size_t)blockIdx.x * 256 + threadIdx.x;
    if (idx >= (size_t)NB * C_OUT * HH * WW) return;
    int ow = idx % WW;
    int oh = (idx / WW) % HH;
    int co = (idx / (HH * WW)) % C_OUT;
    int n  = idx / ((size_t)C_OUT * HH * WW);
    float s = bias[co];
    for (int ci = 0; ci < C_IN; ++ci) {
        const float* xp = x + ((size_t)(n * C_IN + ci) * HH) * WW;
        const float* wp = w + ((size_t)co * C_IN + ci) * 9;
        #pragma unroll
        for (int kh = 0; kh < 3; ++kh) {
            int ihh = oh + kh - 1;
            if (ihh < 0 || ihh >= HH) continue;
            #pragma unroll
            for (int kw = 0; kw < 3; ++kw) {
                int iww = ow + kw - 1;
                if (iww < 0 || iww >= WW) continue;
                s += xp[ihh * WW + iww] * wp[kh * 3 + kw];
            }
        }
    }
    out[idx] = s;
}

extern "C" void kernel_launch(void* const* d_in, const int* in_sizes, int n_in,
                              void* d_out, int out_size, void* d_ws, size_t ws_size,
                              hipStream_t stream) {
    const float* x    = (const float*)d_in[0];
    const float* w    = (const float*)d_in[1];
    const float* bias = (const float*)d_in[2];
    float* out = (float*)d_out;

    const size_t wr_elems = (size_t)9 * C_OUT * C_IN;                   // 73728 shorts
    const size_t xr_elems = (size_t)NB * HH * WW * C_IN;                // 51,380,224 shorts
    const size_t need = (wr_elems + xr_elems) * sizeof(unsigned short); // ~102.9 MB

    if (ws_size >= need) {
        unsigned short* wr = (unsigned short*)d_ws;
        unsigned short* xr = wr + wr_elems;
        wconv_kernel<<<72, 256, 0, stream>>>(w, wr);
        xconv_kernel<<<NB * HH, 256, 0, stream>>>(x, xr);
        conv_main<<<NB * HH * 2, 256, 0, stream>>>(xr, wr, bias, out);
    } else {
        size_t total = (size_t)NB * C_OUT * HH * WW;
        conv_naive<<<(unsigned)((total + 255) / 256), 256, 0, stream>>>(x, w, bias, out);
    }
}